// Round 9
// baseline (516.789 us; speedup 1.0000x reference)
//
#include <hip/hip_runtime.h>
#include <hip/hip_fp16.h>
#include <math.h>

#define N_NODES 100000
#define N_EDGES 3200000
#define F_IN    128
#define F_HID   32
#define F_OUT   40
#define NBINS   ((N_NODES + 255) >> 8)   // 391 coarse bins of 256 nodes
#define EPB     4096                     // edges per block in partition pass A
#define NBLK    ((N_EDGES + EPB - 1) / EPB)
#define BKT_CAP (N_EDGES + 8 * N_NODES)  // room for per-node pad-to-8

typedef _Float16 h2_t __attribute__((ext_vector_type(2)));
__device__ __forceinline__ float fdot2u(unsigned a, unsigned b, float c) {
    return __builtin_amdgcn_fdot2(__builtin_bit_cast(h2_t, a),
                                  __builtin_bit_cast(h2_t, b), c, false);
}

// ---------------------------------------------------------------------------
// GEMM1: h1h[N,32] = fp16(x[N,128] @ W1[128,32])
// ---------------------------------------------------------------------------
__global__ __launch_bounds__(256) void gemm1_kernel(const float* __restrict__ x,
                                                    const float* __restrict__ W,
                                                    __half* __restrict__ h1h) {
    __shared__ float Ws[F_IN * F_HID];     // 16 KB
    __shared__ float Xs[32][F_IN + 4];
    const int tid  = threadIdx.x;
    const int row0 = blockIdx.x * 32;

    for (int i = tid; i < (F_IN * F_HID) / 4; i += 256)
        ((float4*)Ws)[i] = ((const float4*)W)[i];

    for (int i = tid; i < 1024; i += 256) {
        int r = i >> 5;
        int c = i & 31;
        ((float4*)&Xs[r][0])[c] = ((const float4*)x)[(size_t)(row0 + r) * (F_IN / 4) + c];
    }
    __syncthreads();

    const int r  = tid >> 3;
    const int c0 = (tid & 7) * 4;
    float a0 = 0.f, a1 = 0.f, a2 = 0.f, a3 = 0.f;
    for (int k = 0; k < F_IN; ++k) {
        const float xv = Xs[r][k];
        const float* wrow = &Ws[k * F_HID + c0];
        a0 += xv * wrow[0];
        a1 += xv * wrow[1];
        a2 += xv * wrow[2];
        a3 += xv * wrow[3];
    }
    const int row = row0 + r;   // grid exact: 3125*32 == N_NODES
    __half2* o = (__half2*)(h1h + (size_t)row * F_HID + c0);
    o[0] = __floats2half2_rn(a0, a1);
    o[1] = __floats2half2_rn(a2, a3);
}

// ---------------------------------------------------------------------------
// Fused histograms: coarse-bin counts (LDS) + per-node counts (global).
// ---------------------------------------------------------------------------
__global__ __launch_bounds__(256) void binhist_kernel(const int* __restrict__ ei,
                                                      int* __restrict__ bincnt,
                                                      int* __restrict__ cnt) {
    __shared__ int lc[NBINS];
    for (int i = threadIdx.x; i < NBINS; i += 256) lc[i] = 0;
    __syncthreads();
    const int stride = gridDim.x * 256;
    for (int e = blockIdx.x * 256 + threadIdx.x; e < N_EDGES; e += stride) {
        const int d = ei[N_EDGES + e];
        atomicAdd(&lc[d >> 8], 1);
        atomicAdd(&cnt[d], 1);
    }
    __syncthreads();
    for (int i = threadIdx.x; i < NBINS; i += 256)
        if (lc[i]) atomicAdd(&bincnt[i], lc[i]);
}

// ---------------------------------------------------------------------------
// Scan over 391 bin counts -> binbase[0..NBINS] (stg layout) + cursor.
// ---------------------------------------------------------------------------
__global__ __launch_bounds__(512) void binscan_kernel(const int* __restrict__ bincnt,
                                                      int* __restrict__ binbase,
                                                      int* __restrict__ cursor) {
    __shared__ int s[512];
    const int t = threadIdx.x;
    const int v = (t < NBINS) ? bincnt[t] : 0;
    s[t] = v;
    __syncthreads();
    for (int off = 1; off < 512; off <<= 1) {
        int u = (t >= off) ? s[t - off] : 0;
        __syncthreads();
        s[t] += u;
        __syncthreads();
    }
    const int excl = s[t] - v;
    if (t <= NBINS) binbase[t] = excl;
    if (t < NBINS)  cursor[t]  = excl;
}

// ---------------------------------------------------------------------------
// Node scan: offs[n] = exclusive scan of per-node counts PADDED to mult of 8
// (bkt layout). offs[N] = padded total.
// ---------------------------------------------------------------------------
__global__ __launch_bounds__(1024) void nodescan_kernel(const int* __restrict__ cnt,
                                                        int* __restrict__ offs) {
    __shared__ int s[1024];
    const int t = threadIdx.x;
    const int CH = (N_NODES + 1023) / 1024;   // 98
    const int lo = t * CH;
    const int hi = min(lo + CH, N_NODES);
    int sum = 0;
    for (int i = lo; i < hi; ++i) sum += (cnt[i] + 7) & ~7;
    s[t] = sum;
    __syncthreads();
    for (int off = 1; off < 1024; off <<= 1) {
        int u = (t >= off) ? s[t - off] : 0;
        __syncthreads();
        s[t] += u;
        __syncthreads();
    }
    int run = s[t] - sum;
    for (int i = lo; i < hi; ++i) {
        offs[i] = run;
        run += (cnt[i] + 7) & ~7;
    }
    if (hi == N_NODES) offs[N_NODES] = run;   // includes all lo>=N threads (run==total)
}

// ---------------------------------------------------------------------------
// Pass A: LDS-staged multisplit into 391 coarse bins (round-8 version).
// Staged entry: .x = src(17b) | dst_low8 << 17, .y = weight fp32 bits.
// ---------------------------------------------------------------------------
__global__ __launch_bounds__(256) void partA_kernel(const int* __restrict__ ei,
                                                    const float* __restrict__ ew,
                                                    int* __restrict__ cursor,
                                                    int2* __restrict__ stg) {
    __shared__ int lhist[512];
    __shared__ int lscan[512];
    __shared__ int lcur[512];
    __shared__ int lbase[512];
    __shared__ int stmp[256];
    __shared__ int2 lstg[EPB];                 // 32 KB
    __shared__ unsigned short lbin[EPB];       // 8 KB
    const int tid = threadIdx.x;
    const int e0  = blockIdx.x * EPB;
    const int tot = min(EPB, N_EDGES - e0);

    lhist[tid] = 0; lhist[tid + 256] = 0;
    __syncthreads();

    for (int base = 0; base < EPB; base += 1024) {
        int d0 = -1, d1 = -1, d2 = -1, d3 = -1;
        const int e = e0 + base + tid;
        if (e < N_EDGES)       d0 = ei[N_EDGES + e] >> 8;
        if (e + 256 < N_EDGES) d1 = ei[N_EDGES + e + 256] >> 8;
        if (e + 512 < N_EDGES) d2 = ei[N_EDGES + e + 512] >> 8;
        if (e + 768 < N_EDGES) d3 = ei[N_EDGES + e + 768] >> 8;
        if (d0 >= 0) atomicAdd(&lhist[d0], 1);
        if (d1 >= 0) atomicAdd(&lhist[d1], 1);
        if (d2 >= 0) atomicAdd(&lhist[d2], 1);
        if (d3 >= 0) atomicAdd(&lhist[d3], 1);
    }
    __syncthreads();

    const int ca = lhist[2 * tid];
    const int cb = lhist[2 * tid + 1];
    const int pair = ca + cb;
    stmp[tid] = pair;
    __syncthreads();
    for (int off = 1; off < 256; off <<= 1) {
        int u = (tid >= off) ? stmp[tid - off] : 0;
        __syncthreads();
        stmp[tid] += u;
        __syncthreads();
    }
    const int pexcl = stmp[tid] - pair;
    lscan[2 * tid]     = pexcl;
    lscan[2 * tid + 1] = pexcl + ca;
    lcur[2 * tid]      = pexcl;
    lcur[2 * tid + 1]  = pexcl + ca;
    __syncthreads();

    for (int b = tid; b < NBINS; b += 256) {
        const int c = lhist[b];
        lbase[b] = c ? atomicAdd(&cursor[b], c) : 0;
    }
    __syncthreads();

    for (int base = 0; base < EPB; base += 1024) {
        int s0 = 0, s1 = 0, s2 = 0, s3 = 0;
        int d0 = -1, d1 = -1, d2 = -1, d3 = -1;
        float w0 = 0.f, w1 = 0.f, w2 = 0.f, w3 = 0.f;
        const int e = e0 + base + tid;
        if (e < N_EDGES)       { s0 = ei[e];       d0 = ei[N_EDGES + e];       w0 = ew[e]; }
        if (e + 256 < N_EDGES) { s1 = ei[e + 256]; d1 = ei[N_EDGES + e + 256]; w1 = ew[e + 256]; }
        if (e + 512 < N_EDGES) { s2 = ei[e + 512]; d2 = ei[N_EDGES + e + 512]; w2 = ew[e + 512]; }
        if (e + 768 < N_EDGES) { s3 = ei[e + 768]; d3 = ei[N_EDGES + e + 768]; w3 = ew[e + 768]; }
        if (d0 >= 0) {
            const int b = d0 >> 8;
            const int p = atomicAdd(&lcur[b], 1);
            lstg[p] = make_int2(s0 | ((d0 & 255) << 17), __float_as_int(w0));
            lbin[p] = (unsigned short)b;
        }
        if (d1 >= 0) {
            const int b = d1 >> 8;
            const int p = atomicAdd(&lcur[b], 1);
            lstg[p] = make_int2(s1 | ((d1 & 255) << 17), __float_as_int(w1));
            lbin[p] = (unsigned short)b;
        }
        if (d2 >= 0) {
            const int b = d2 >> 8;
            const int p = atomicAdd(&lcur[b], 1);
            lstg[p] = make_int2(s2 | ((d2 & 255) << 17), __float_as_int(w2));
            lbin[p] = (unsigned short)b;
        }
        if (d3 >= 0) {
            const int b = d3 >> 8;
            const int p = atomicAdd(&lcur[b], 1);
            lstg[p] = make_int2(s3 | ((d3 & 255) << 17), __float_as_int(w3));
            lbin[p] = (unsigned short)b;
        }
    }
    __syncthreads();

    for (int i = tid; i < tot; i += 256) {
        const int b = lbin[i];
        stg[lbase[b] + (i - lscan[b])] = lstg[i];
    }
}

// ---------------------------------------------------------------------------
// Pass B: one block per bin. Cursors init from padded offs; place packed 4B
// entries src(17b) | fp16bits(w)<<17; zero-fill the padding slots.
// ---------------------------------------------------------------------------
__global__ __launch_bounds__(256) void partB_kernel(const int* __restrict__ binbase,
                                                    const int2* __restrict__ stg,
                                                    const int* __restrict__ offs,
                                                    int* __restrict__ bkt) {
    __shared__ int lcur[256];
    const int tid  = threadIdx.x;
    const int b    = blockIdx.x;
    const int node = (b << 8) + tid;
    int pend = 0;
    if (node < N_NODES) {
        lcur[tid] = offs[node];
        pend = offs[node + 1];
    } else {
        lcur[tid] = 0;
    }
    __syncthreads();

    const int start = binbase[b];
    const int end   = binbase[b + 1];
    for (int j = start + tid; j < end; j += 256) {
        const int2 p = stg[j];
        const int dlow = (p.x >> 17) & 255;
        const unsigned hb = __half_as_ushort(__float2half(__int_as_float(p.y)));
        const int pos = atomicAdd(&lcur[dlow], 1);
        bkt[pos] = (p.x & 0x1FFFF) | ((int)hb << 17);
    }
    __syncthreads();

    if (node < N_NODES)
        for (int k = lcur[tid]; k < pend; ++k) bkt[k] = 0;
}

// ---------------------------------------------------------------------------
// Shared gather core. Segment [j, jend) is a multiple of 8 entries, j mult 8.
// 8 groups x 8 lanes; lane holds an 8B (4-feature) row fragment.
// Main loop: 4 edges/group via dwordx4 + v_perm pairing + v_dot2_f32_f16.
// ---------------------------------------------------------------------------
__device__ __forceinline__ void gather_acc(const int* __restrict__ bkt,
                                           int j, const int jend,
                                           const char* __restrict__ tbl,
                                           const unsigned sub8, const int g,
                                           float& a0, float& a1, float& a2, float& a3) {
#define PAIR_BODY(PX, PY, RA, RB)                                               \
    {                                                                           \
        const unsigned wp = __builtin_amdgcn_perm((unsigned)(PY) >> 17,         \
                                                  (unsigned)(PX) >> 17,         \
                                                  0x05040100u);                 \
        a0 = fdot2u(__builtin_amdgcn_perm((RB).x, (RA).x, 0x05040100u), wp, a0);\
        a1 = fdot2u(__builtin_amdgcn_perm((RB).x, (RA).x, 0x07060302u), wp, a1);\
        a2 = fdot2u(__builtin_amdgcn_perm((RB).y, (RA).y, 0x05040100u), wp, a2);\
        a3 = fdot2u(__builtin_amdgcn_perm((RB).y, (RA).y, 0x07060302u), wp, a3);\
    }
    for (; j + 32 <= jend; j += 32) {
        const int4 pq = *(const int4*)&bkt[j + 4 * g];
        const uint2 r0 = *(const uint2*)(tbl + (((unsigned)pq.x & 0x1FFFFu) << 6) + sub8);
        const uint2 r1 = *(const uint2*)(tbl + (((unsigned)pq.y & 0x1FFFFu) << 6) + sub8);
        const uint2 r2 = *(const uint2*)(tbl + (((unsigned)pq.z & 0x1FFFFu) << 6) + sub8);
        const uint2 r3 = *(const uint2*)(tbl + (((unsigned)pq.w & 0x1FFFFu) << 6) + sub8);
        PAIR_BODY(pq.x, pq.y, r0, r1);
        PAIR_BODY(pq.z, pq.w, r2, r3);
    }
    if (j + 16 <= jend) {
        const int2 pp = *(const int2*)&bkt[j + 2 * g];
        const uint2 r0 = *(const uint2*)(tbl + (((unsigned)pp.x & 0x1FFFFu) << 6) + sub8);
        const uint2 r1 = *(const uint2*)(tbl + (((unsigned)pp.y & 0x1FFFFu) << 6) + sub8);
        PAIR_BODY(pp.x, pp.y, r0, r1);
        j += 16;
    }
    if (j < jend) {   // exactly 8 remain
        const unsigned p = (unsigned)bkt[j + g];
        const unsigned w = p >> 17;            // high half zero
        const uint2 rv = *(const uint2*)(tbl + ((p & 0x1FFFFu) << 6) + sub8);
        a0 = fdot2u(rv.x & 0xFFFFu, w, a0);
        a1 = fdot2u(rv.x >> 16,     w, a1);
        a2 = fdot2u(rv.y & 0xFFFFu, w, a2);
        a3 = fdot2u(rv.y >> 16,     w, a3);
    }
#undef PAIR_BODY
}

// ---------------------------------------------------------------------------
// Gather 1 + bias1 + ReLU: rh[n] = fp16(relu(sum_e w_e * h1h[src_e] + b1))
// ---------------------------------------------------------------------------
__global__ __launch_bounds__(256) void gather1_kernel(const int* __restrict__ offs,
                                                      const int* __restrict__ bkt,
                                                      const __half* __restrict__ h1h,
                                                      const float* __restrict__ b1,
                                                      __half* __restrict__ rh) {
    const int wave = threadIdx.x >> 6, lane = threadIdx.x & 63;
    const int node = blockIdx.x * 4 + wave;          // grid exact: 25000*4
    const int g    = lane >> 3;
    const int sub  = lane & 7;
    const unsigned sub8 = sub * 8;

    float a0 = 0.f, a1 = 0.f, a2 = 0.f, a3 = 0.f;
    gather_acc(bkt, offs[node], offs[node + 1], (const char*)h1h, sub8, g,
               a0, a1, a2, a3);
    #pragma unroll
    for (int off = 8; off < 64; off <<= 1) {
        a0 += __shfl_xor(a0, off);
        a1 += __shfl_xor(a1, off);
        a2 += __shfl_xor(a2, off);
        a3 += __shfl_xor(a3, off);
    }
    if (g == 0) {
        const float4 bb = ((const float4*)b1)[sub];
        a0 = fmaxf(a0 + bb.x, 0.f);
        a1 = fmaxf(a1 + bb.y, 0.f);
        a2 = fmaxf(a2 + bb.z, 0.f);
        a3 = fmaxf(a3 + bb.w, 0.f);
        uint2 o;
        *(__half2*)&o.x = __floats2half2_rn(a0, a1);
        *(__half2*)&o.y = __floats2half2_rn(a2, a3);
        *(uint2*)((char*)rh + (size_t)node * 64 + sub8) = o;
    }
}

// ---------------------------------------------------------------------------
// Gather 2 + GEMM2 + bias2 + log-softmax, all fused. One wave per node.
// ---------------------------------------------------------------------------
__global__ __launch_bounds__(256) void gather2_lsm_kernel(const int* __restrict__ offs,
                                                          const int* __restrict__ bkt,
                                                          const __half* __restrict__ rh,
                                                          const float* __restrict__ W2,
                                                          const float* __restrict__ b2,
                                                          float* __restrict__ out) {
    __shared__ float W2s[F_HID * F_OUT];   // 5 KB
    __shared__ float rb[4][F_HID];
    const int tid = threadIdx.x;
    for (int i = tid; i < F_HID * F_OUT; i += 256) W2s[i] = W2[i];

    const int wave = tid >> 6, lane = tid & 63;
    const int node = blockIdx.x * 4 + wave;          // grid exact
    const int g    = lane >> 3;
    const int sub  = lane & 7;
    const unsigned sub8 = sub * 8;

    float a0 = 0.f, a1 = 0.f, a2 = 0.f, a3 = 0.f;
    gather_acc(bkt, offs[node], offs[node + 1], (const char*)rh, sub8, g,
               a0, a1, a2, a3);
    #pragma unroll
    for (int off = 8; off < 64; off <<= 1) {
        a0 += __shfl_xor(a0, off);
        a1 += __shfl_xor(a1, off);
        a2 += __shfl_xor(a2, off);
        a3 += __shfl_xor(a3, off);
    }
    if (g == 0)
        ((float4*)&rb[wave][0])[sub] = make_float4(a0, a1, a2, a3);
    __syncthreads();

    float val = -INFINITY;
    if (lane < F_OUT) {
        float acc = b2[lane];
        #pragma unroll
        for (int k = 0; k < F_HID; ++k)
            acc += rb[wave][k] * W2s[k * F_OUT + lane];
        val = acc;
    }
    float m = val;
    for (int off = 32; off; off >>= 1) m = fmaxf(m, __shfl_xor(m, off));
    float ex = (lane < F_OUT) ? __expf(val - m) : 0.f;
    for (int off = 32; off; off >>= 1) ex += __shfl_xor(ex, off);
    if (lane < F_OUT) out[(size_t)node * F_OUT + lane] = val - m - __logf(ex);
}

// ---------------------------------------------------------------------------
extern "C" void kernel_launch(void* const* d_in, const int* in_sizes, int n_in,
                              void* d_out, int out_size, void* d_ws, size_t ws_size,
                              hipStream_t stream) {
    const float* x  = (const float*)d_in[0];
    const int*   ei = (const int*)d_in[1];    // [2, E] int32: row 0 = src, row 1 = dst
    const float* ew = (const float*)d_in[2];
    const float* W1 = (const float*)d_in[3];
    const float* b1 = (const float*)d_in[4];
    const float* W2 = (const float*)d_in[5];
    const float* b2 = (const float*)d_in[6];
    float* out = (float*)d_out;

    // Workspace layout (16B-aligned):
    //   bincnt  : NBINS ints
    //   binbase : NBINS+1 ints
    //   cursor  : NBINS ints
    //   cnt     : N ints            0.4 MB   (raw per-node degree)
    //   offs    : N+1 ints          0.4 MB   (padded-to-8 bkt offsets)
    //   bkt     : BKT_CAP ints     16.0 MB
    //   union   : stg[E] int2 (25.6 MB, build only)  /  h1h + rh fp16 (12.8 MB)
    char* p = (char*)d_ws;
    size_t off = 0;
    auto alloc = [&](size_t bytes) {
        char* r = p + off;
        off += (bytes + 15) & ~(size_t)15;
        return r;
    };
    int*   bincnt  = (int*)  alloc((size_t)NBINS * 4);
    int*   binbase = (int*)  alloc((size_t)(NBINS + 1) * 4);
    int*   cursor  = (int*)  alloc((size_t)NBINS * 4);
    int*   cnt     = (int*)  alloc((size_t)N_NODES * 4);
    int*   offs    = (int*)  alloc((size_t)(N_NODES + 1) * 4);
    int*   bkt     = (int*)  alloc((size_t)BKT_CAP * 4);
    char*  uni     = (char*) alloc((size_t)N_EDGES * 8);   // stg is the larger member
    int2*  stg     = (int2*)uni;
    __half* h1h    = (__half*)uni;
    __half* rh     = h1h + (size_t)N_NODES * F_HID;

    // --- CSR build (dst-major, node segments padded to multiples of 8) ---
    hipMemsetAsync(bincnt, 0, (size_t)NBINS * 4, stream);
    hipMemsetAsync(cnt, 0, (size_t)N_NODES * 4, stream);
    binhist_kernel<<<1024, 256, 0, stream>>>(ei, bincnt, cnt);
    binscan_kernel<<<1, 512, 0, stream>>>(bincnt, binbase, cursor);
    nodescan_kernel<<<1, 1024, 0, stream>>>(cnt, offs);
    partA_kernel<<<NBLK, 256, 0, stream>>>(ei, ew, cursor, stg);
    partB_kernel<<<NBINS, 256, 0, stream>>>(binbase, stg, offs, bkt);

    // --- Layer 1: h1 = x@W1 (fp16 table), r = relu(agg(h1)+b1) (fp16 table) ---
    gemm1_kernel<<<N_NODES / 32, 256, 0, stream>>>(x, W1, h1h);
    gather1_kernel<<<N_NODES / 4, 256, 0, stream>>>(offs, bkt, h1h, b1, rh);

    // --- Layer 2 (aggregate-then-transform) + bias2 + log-softmax, fused ---
    gather2_lsm_kernel<<<N_NODES / 4, 256, 0, stream>>>(offs, bkt, rh, W2, b2, out);
}

// Round 10
// 256.232 us; speedup vs baseline: 2.0169x; 2.0169x over previous
//
#include <hip/hip_runtime.h>
#include <hip/hip_fp16.h>
#include <math.h>

#define N_NODES 100000
#define N_EDGES 3200000
#define F_IN    128
#define F_HID   32
#define F_OUT   40
#define NBINS   ((N_NODES + 255) >> 8)   // 391 coarse bins of 256 nodes
#define EPB     4096                     // edges per block in partition pass A
#define NBLK    ((N_EDGES + EPB - 1) / EPB)
#define BKT_CAP (N_EDGES + 8 * N_NODES)  // room for per-node pad-to-8

typedef _Float16 h2_t __attribute__((ext_vector_type(2)));
__device__ __forceinline__ float fdot2u(unsigned a, unsigned b, float c) {
    return __builtin_amdgcn_fdot2(__builtin_bit_cast(h2_t, a),
                                  __builtin_bit_cast(h2_t, b), c, false);
}

// ---------------------------------------------------------------------------
// GEMM1: h1h[N,32] = fp16(x[N,128] @ W1[128,32])
// ---------------------------------------------------------------------------
__global__ __launch_bounds__(256) void gemm1_kernel(const float* __restrict__ x,
                                                    const float* __restrict__ W,
                                                    __half* __restrict__ h1h) {
    __shared__ float Ws[F_IN * F_HID];     // 16 KB
    __shared__ float Xs[32][F_IN + 4];
    const int tid  = threadIdx.x;
    const int row0 = blockIdx.x * 32;

    for (int i = tid; i < (F_IN * F_HID) / 4; i += 256)
        ((float4*)Ws)[i] = ((const float4*)W)[i];

    for (int i = tid; i < 1024; i += 256) {
        int r = i >> 5;
        int c = i & 31;
        ((float4*)&Xs[r][0])[c] = ((const float4*)x)[(size_t)(row0 + r) * (F_IN / 4) + c];
    }
    __syncthreads();

    const int r  = tid >> 3;
    const int c0 = (tid & 7) * 4;
    float a0 = 0.f, a1 = 0.f, a2 = 0.f, a3 = 0.f;
    for (int k = 0; k < F_IN; ++k) {
        const float xv = Xs[r][k];
        const float* wrow = &Ws[k * F_HID + c0];
        a0 += xv * wrow[0];
        a1 += xv * wrow[1];
        a2 += xv * wrow[2];
        a3 += xv * wrow[3];
    }
    const int row = row0 + r;   // grid exact: 3125*32 == N_NODES
    __half2* o = (__half2*)(h1h + (size_t)row * F_HID + c0);
    o[0] = __floats2half2_rn(a0, a1);
    o[1] = __floats2half2_rn(a2, a3);
}

// ---------------------------------------------------------------------------
// Coarse-bin histogram (391 bins), LDS-aggregated (round-8 form).
// ---------------------------------------------------------------------------
__global__ __launch_bounds__(256) void binhist_kernel(const int* __restrict__ ei,
                                                      int* __restrict__ bincnt) {
    __shared__ int lc[NBINS];
    for (int i = threadIdx.x; i < NBINS; i += 256) lc[i] = 0;
    __syncthreads();
    const int stride = gridDim.x * 256;
    for (int e = blockIdx.x * 256 + threadIdx.x; e < N_EDGES; e += stride)
        atomicAdd(&lc[ei[N_EDGES + e] >> 8], 1);
    __syncthreads();
    for (int i = threadIdx.x; i < NBINS; i += 256)
        if (lc[i]) atomicAdd(&bincnt[i], lc[i]);
}

// ---------------------------------------------------------------------------
// Scan over 391 bin counts -> binbase[0..NBINS] (stg layout) + cursor.
// ---------------------------------------------------------------------------
__global__ __launch_bounds__(512) void binscan_kernel(const int* __restrict__ bincnt,
                                                      int* __restrict__ binbase,
                                                      int* __restrict__ cursor) {
    __shared__ int s[512];
    const int t = threadIdx.x;
    const int v = (t < NBINS) ? bincnt[t] : 0;
    s[t] = v;
    __syncthreads();
    for (int off = 1; off < 512; off <<= 1) {
        int u = (t >= off) ? s[t - off] : 0;
        __syncthreads();
        s[t] += u;
        __syncthreads();
    }
    const int excl = s[t] - v;
    if (t <= NBINS) binbase[t] = excl;
    if (t < NBINS)  cursor[t]  = excl;
}

// ---------------------------------------------------------------------------
// Pass A: LDS-staged multisplit into 391 coarse bins (round-8 version).
// Staged entry: .x = src(17b) | dst_low8 << 17, .y = weight fp32 bits.
// ---------------------------------------------------------------------------
__global__ __launch_bounds__(256) void partA_kernel(const int* __restrict__ ei,
                                                    const float* __restrict__ ew,
                                                    int* __restrict__ cursor,
                                                    int2* __restrict__ stg) {
    __shared__ int lhist[512];
    __shared__ int lscan[512];
    __shared__ int lcur[512];
    __shared__ int lbase[512];
    __shared__ int stmp[256];
    __shared__ int2 lstg[EPB];                 // 32 KB
    __shared__ unsigned short lbin[EPB];       // 8 KB
    const int tid = threadIdx.x;
    const int e0  = blockIdx.x * EPB;
    const int tot = min(EPB, N_EDGES - e0);

    lhist[tid] = 0; lhist[tid + 256] = 0;
    __syncthreads();

    for (int base = 0; base < EPB; base += 1024) {
        int d0 = -1, d1 = -1, d2 = -1, d3 = -1;
        const int e = e0 + base + tid;
        if (e < N_EDGES)       d0 = ei[N_EDGES + e] >> 8;
        if (e + 256 < N_EDGES) d1 = ei[N_EDGES + e + 256] >> 8;
        if (e + 512 < N_EDGES) d2 = ei[N_EDGES + e + 512] >> 8;
        if (e + 768 < N_EDGES) d3 = ei[N_EDGES + e + 768] >> 8;
        if (d0 >= 0) atomicAdd(&lhist[d0], 1);
        if (d1 >= 0) atomicAdd(&lhist[d1], 1);
        if (d2 >= 0) atomicAdd(&lhist[d2], 1);
        if (d3 >= 0) atomicAdd(&lhist[d3], 1);
    }
    __syncthreads();

    const int ca = lhist[2 * tid];
    const int cb = lhist[2 * tid + 1];
    const int pair = ca + cb;
    stmp[tid] = pair;
    __syncthreads();
    for (int off = 1; off < 256; off <<= 1) {
        int u = (tid >= off) ? stmp[tid - off] : 0;
        __syncthreads();
        stmp[tid] += u;
        __syncthreads();
    }
    const int pexcl = stmp[tid] - pair;
    lscan[2 * tid]     = pexcl;
    lscan[2 * tid + 1] = pexcl + ca;
    lcur[2 * tid]      = pexcl;
    lcur[2 * tid + 1]  = pexcl + ca;
    __syncthreads();

    for (int b = tid; b < NBINS; b += 256) {
        const int c = lhist[b];
        lbase[b] = c ? atomicAdd(&cursor[b], c) : 0;
    }
    __syncthreads();

    for (int base = 0; base < EPB; base += 1024) {
        int s0 = 0, s1 = 0, s2 = 0, s3 = 0;
        int d0 = -1, d1 = -1, d2 = -1, d3 = -1;
        float w0 = 0.f, w1 = 0.f, w2 = 0.f, w3 = 0.f;
        const int e = e0 + base + tid;
        if (e < N_EDGES)       { s0 = ei[e];       d0 = ei[N_EDGES + e];       w0 = ew[e]; }
        if (e + 256 < N_EDGES) { s1 = ei[e + 256]; d1 = ei[N_EDGES + e + 256]; w1 = ew[e + 256]; }
        if (e + 512 < N_EDGES) { s2 = ei[e + 512]; d2 = ei[N_EDGES + e + 512]; w2 = ew[e + 512]; }
        if (e + 768 < N_EDGES) { s3 = ei[e + 768]; d3 = ei[N_EDGES + e + 768]; w3 = ew[e + 768]; }
        if (d0 >= 0) {
            const int b = d0 >> 8;
            const int p = atomicAdd(&lcur[b], 1);
            lstg[p] = make_int2(s0 | ((d0 & 255) << 17), __float_as_int(w0));
            lbin[p] = (unsigned short)b;
        }
        if (d1 >= 0) {
            const int b = d1 >> 8;
            const int p = atomicAdd(&lcur[b], 1);
            lstg[p] = make_int2(s1 | ((d1 & 255) << 17), __float_as_int(w1));
            lbin[p] = (unsigned short)b;
        }
        if (d2 >= 0) {
            const int b = d2 >> 8;
            const int p = atomicAdd(&lcur[b], 1);
            lstg[p] = make_int2(s2 | ((d2 & 255) << 17), __float_as_int(w2));
            lbin[p] = (unsigned short)b;
        }
        if (d3 >= 0) {
            const int b = d3 >> 8;
            const int p = atomicAdd(&lcur[b], 1);
            lstg[p] = make_int2(s3 | ((d3 & 255) << 17), __float_as_int(w3));
            lbin[p] = (unsigned short)b;
        }
    }
    __syncthreads();

    for (int i = tid; i < tot; i += 256) {
        const int b = lbin[i];
        stg[lbase[b] + (i - lscan[b])] = lstg[i];
    }
}

// ---------------------------------------------------------------------------
// Pass B1: one block per bin. Count per-node degrees from the bin's stg
// slice (LDS atomics), pad to 8, in-LDS scan -> in-bin offsets offsIB and
// padded bin total pbt[b]. Fully parallel (replaces the serial nodescan).
// ---------------------------------------------------------------------------
__global__ __launch_bounds__(256) void partB1_kernel(const int* __restrict__ binbase,
                                                     const int2* __restrict__ stg,
                                                     int* __restrict__ offsIB,
                                                     int* __restrict__ pbt) {
    __shared__ int lcnt[256];
    __shared__ int lsc[256];
    const int tid   = threadIdx.x;
    const int b     = blockIdx.x;
    const int start = binbase[b];
    const int end   = binbase[b + 1];

    lcnt[tid] = 0;
    __syncthreads();
    for (int j = start + tid; j < end; j += 256)
        atomicAdd(&lcnt[(((const int*)stg)[2 * j] >> 17) & 255], 1);
    __syncthreads();

    const int padded = (lcnt[tid] + 7) & ~7;
    lsc[tid] = padded;
    __syncthreads();
    for (int off = 1; off < 256; off <<= 1) {
        int u = (tid >= off) ? lsc[tid - off] : 0;
        __syncthreads();
        lsc[tid] += u;
        __syncthreads();
    }
    offsIB[(b << 8) + tid] = lsc[tid] - padded;    // in-bin exclusive
    if (tid == 255) pbt[b] = lsc[255];             // padded bin total
}

// ---------------------------------------------------------------------------
// Scan over 391 padded bin totals -> pbb[0..NBINS]; offs[N] = padded total.
// ---------------------------------------------------------------------------
__global__ __launch_bounds__(512) void padscan_kernel(const int* __restrict__ pbt,
                                                      int* __restrict__ pbb,
                                                      int* __restrict__ offs) {
    __shared__ int s[512];
    const int t = threadIdx.x;
    const int v = (t < NBINS) ? pbt[t] : 0;
    s[t] = v;
    __syncthreads();
    for (int off = 1; off < 512; off <<= 1) {
        int u = (t >= off) ? s[t - off] : 0;
        __syncthreads();
        s[t] += u;
        __syncthreads();
    }
    const int excl = s[t] - v;
    if (t <= NBINS) pbb[t] = excl;
    if (t == NBINS) offs[N_NODES] = excl;
}

// ---------------------------------------------------------------------------
// Pass B2: one block per bin. Final base = pbb[b] + offsIB; write offs[node],
// place packed 4B entries src(17b)|fp16bits(w)<<17, zero-fill the pad slots.
// ---------------------------------------------------------------------------
__global__ __launch_bounds__(256) void partB2_kernel(const int* __restrict__ binbase,
                                                     const int2* __restrict__ stg,
                                                     const int* __restrict__ pbb,
                                                     const int* __restrict__ offsIB,
                                                     int* __restrict__ offs,
                                                     int* __restrict__ bkt) {
    __shared__ int lcur[256];
    const int tid  = threadIdx.x;
    const int b    = blockIdx.x;
    const int node = (b << 8) + tid;
    const int base = pbb[b] + offsIB[node];
    const int pend = (tid < 255) ? (pbb[b] + offsIB[node + 1]) : pbb[b + 1];
    lcur[tid] = base;
    if (node < N_NODES) offs[node] = base;
    __syncthreads();

    const int start = binbase[b];
    const int end   = binbase[b + 1];
    for (int j = start + tid; j < end; j += 256) {
        const int2 p = stg[j];
        const int dlow = (p.x >> 17) & 255;
        const unsigned hb = __half_as_ushort(__float2half(__int_as_float(p.y)));
        const int pos = atomicAdd(&lcur[dlow], 1);
        bkt[pos] = (p.x & 0x1FFFF) | ((int)hb << 17);
    }
    __syncthreads();

    for (int k = lcur[tid]; k < pend; ++k) bkt[k] = 0;
}

// ---------------------------------------------------------------------------
// Shared gather core. Segment [j, jend) is a multiple of 8 entries, j mult 8.
// 8 groups x 8 lanes; lane holds an 8B (4-feature) row fragment.
// Main loop: 4 edges/group via dwordx4 + v_perm pairing + v_dot2_f32_f16.
// ---------------------------------------------------------------------------
__device__ __forceinline__ void gather_acc(const int* __restrict__ bkt,
                                           int j, const int jend,
                                           const char* __restrict__ tbl,
                                           const unsigned sub8, const int g,
                                           float& a0, float& a1, float& a2, float& a3) {
#define PAIR_BODY(PX, PY, RA, RB)                                               \
    {                                                                           \
        const unsigned wp = __builtin_amdgcn_perm((unsigned)(PY) >> 17,         \
                                                  (unsigned)(PX) >> 17,         \
                                                  0x05040100u);                 \
        a0 = fdot2u(__builtin_amdgcn_perm((RB).x, (RA).x, 0x05040100u), wp, a0);\
        a1 = fdot2u(__builtin_amdgcn_perm((RB).x, (RA).x, 0x07060302u), wp, a1);\
        a2 = fdot2u(__builtin_amdgcn_perm((RB).y, (RA).y, 0x05040100u), wp, a2);\
        a3 = fdot2u(__builtin_amdgcn_perm((RB).y, (RA).y, 0x07060302u), wp, a3);\
    }
    for (; j + 32 <= jend; j += 32) {
        const int4 pq = *(const int4*)&bkt[j + 4 * g];
        const uint2 r0 = *(const uint2*)(tbl + (((unsigned)pq.x & 0x1FFFFu) << 6) + sub8);
        const uint2 r1 = *(const uint2*)(tbl + (((unsigned)pq.y & 0x1FFFFu) << 6) + sub8);
        const uint2 r2 = *(const uint2*)(tbl + (((unsigned)pq.z & 0x1FFFFu) << 6) + sub8);
        const uint2 r3 = *(const uint2*)(tbl + (((unsigned)pq.w & 0x1FFFFu) << 6) + sub8);
        PAIR_BODY(pq.x, pq.y, r0, r1);
        PAIR_BODY(pq.z, pq.w, r2, r3);
    }
    if (j + 16 <= jend) {
        const int2 pp = *(const int2*)&bkt[j + 2 * g];
        const uint2 r0 = *(const uint2*)(tbl + (((unsigned)pp.x & 0x1FFFFu) << 6) + sub8);
        const uint2 r1 = *(const uint2*)(tbl + (((unsigned)pp.y & 0x1FFFFu) << 6) + sub8);
        PAIR_BODY(pp.x, pp.y, r0, r1);
        j += 16;
    }
    if (j < jend) {   // exactly 8 remain
        const unsigned p = (unsigned)bkt[j + g];
        const unsigned w = p >> 17;            // high half zero
        const uint2 rv = *(const uint2*)(tbl + ((p & 0x1FFFFu) << 6) + sub8);
        a0 = fdot2u(rv.x & 0xFFFFu, w, a0);
        a1 = fdot2u(rv.x >> 16,     w, a1);
        a2 = fdot2u(rv.y & 0xFFFFu, w, a2);
        a3 = fdot2u(rv.y >> 16,     w, a3);
    }
#undef PAIR_BODY
}

// ---------------------------------------------------------------------------
// Gather 1 + bias1 + ReLU: rh[n] = fp16(relu(sum_e w_e * h1h[src_e] + b1))
// ---------------------------------------------------------------------------
__global__ __launch_bounds__(256) void gather1_kernel(const int* __restrict__ offs,
                                                      const int* __restrict__ bkt,
                                                      const __half* __restrict__ h1h,
                                                      const float* __restrict__ b1,
                                                      __half* __restrict__ rh) {
    const int wave = threadIdx.x >> 6, lane = threadIdx.x & 63;
    const int node = blockIdx.x * 4 + wave;          // grid exact: 25000*4
    const int g    = lane >> 3;
    const int sub  = lane & 7;
    const unsigned sub8 = sub * 8;

    float a0 = 0.f, a1 = 0.f, a2 = 0.f, a3 = 0.f;
    gather_acc(bkt, offs[node], offs[node + 1], (const char*)h1h, sub8, g,
               a0, a1, a2, a3);
    #pragma unroll
    for (int off = 8; off < 64; off <<= 1) {
        a0 += __shfl_xor(a0, off);
        a1 += __shfl_xor(a1, off);
        a2 += __shfl_xor(a2, off);
        a3 += __shfl_xor(a3, off);
    }
    if (g == 0) {
        const float4 bb = ((const float4*)b1)[sub];
        a0 = fmaxf(a0 + bb.x, 0.f);
        a1 = fmaxf(a1 + bb.y, 0.f);
        a2 = fmaxf(a2 + bb.z, 0.f);
        a3 = fmaxf(a3 + bb.w, 0.f);
        uint2 o;
        *(__half2*)&o.x = __floats2half2_rn(a0, a1);
        *(__half2*)&o.y = __floats2half2_rn(a2, a3);
        *(uint2*)((char*)rh + (size_t)node * 64 + sub8) = o;
    }
}

// ---------------------------------------------------------------------------
// Gather 2 + GEMM2 + bias2 + log-softmax, all fused. One wave per node.
// ---------------------------------------------------------------------------
__global__ __launch_bounds__(256) void gather2_lsm_kernel(const int* __restrict__ offs,
                                                          const int* __restrict__ bkt,
                                                          const __half* __restrict__ rh,
                                                          const float* __restrict__ W2,
                                                          const float* __restrict__ b2,
                                                          float* __restrict__ out) {
    __shared__ float W2s[F_HID * F_OUT];   // 5 KB
    __shared__ float rb[4][F_HID];
    const int tid = threadIdx.x;
    for (int i = tid; i < F_HID * F_OUT; i += 256) W2s[i] = W2[i];

    const int wave = tid >> 6, lane = tid & 63;
    const int node = blockIdx.x * 4 + wave;          // grid exact
    const int g    = lane >> 3;
    const int sub  = lane & 7;
    const unsigned sub8 = sub * 8;

    float a0 = 0.f, a1 = 0.f, a2 = 0.f, a3 = 0.f;
    gather_acc(bkt, offs[node], offs[node + 1], (const char*)rh, sub8, g,
               a0, a1, a2, a3);
    #pragma unroll
    for (int off = 8; off < 64; off <<= 1) {
        a0 += __shfl_xor(a0, off);
        a1 += __shfl_xor(a1, off);
        a2 += __shfl_xor(a2, off);
        a3 += __shfl_xor(a3, off);
    }
    if (g == 0)
        ((float4*)&rb[wave][0])[sub] = make_float4(a0, a1, a2, a3);
    __syncthreads();

    float val = -INFINITY;
    if (lane < F_OUT) {
        float acc = b2[lane];
        #pragma unroll
        for (int k = 0; k < F_HID; ++k)
            acc += rb[wave][k] * W2s[k * F_OUT + lane];
        val = acc;
    }
    float m = val;
    for (int off = 32; off; off >>= 1) m = fmaxf(m, __shfl_xor(m, off));
    float ex = (lane < F_OUT) ? __expf(val - m) : 0.f;
    for (int off = 32; off; off >>= 1) ex += __shfl_xor(ex, off);
    if (lane < F_OUT) out[(size_t)node * F_OUT + lane] = val - m - __logf(ex);
}

// ---------------------------------------------------------------------------
extern "C" void kernel_launch(void* const* d_in, const int* in_sizes, int n_in,
                              void* d_out, int out_size, void* d_ws, size_t ws_size,
                              hipStream_t stream) {
    const float* x  = (const float*)d_in[0];
    const int*   ei = (const int*)d_in[1];    // [2, E] int32: row 0 = src, row 1 = dst
    const float* ew = (const float*)d_in[2];
    const float* W1 = (const float*)d_in[3];
    const float* b1 = (const float*)d_in[4];
    const float* W2 = (const float*)d_in[5];
    const float* b2 = (const float*)d_in[6];
    float* out = (float*)d_out;

    // Workspace layout (16B-aligned):
    //   bincnt  : NBINS ints
    //   binbase : NBINS+1 ints
    //   cursor  : NBINS ints
    //   pbt     : NBINS ints
    //   pbb     : NBINS+1 ints
    //   offsIB  : NBINS*256 ints    0.4 MB
    //   offs    : N+1 ints          0.4 MB
    //   bkt     : BKT_CAP ints     16.0 MB
    //   union   : stg[E] int2 (25.6 MB, build only)  /  h1h + rh fp16 (12.8 MB)
    char* p = (char*)d_ws;
    size_t off = 0;
    auto alloc = [&](size_t bytes) {
        char* r = p + off;
        off += (bytes + 15) & ~(size_t)15;
        return r;
    };
    int*   bincnt  = (int*)  alloc((size_t)NBINS * 4);
    int*   binbase = (int*)  alloc((size_t)(NBINS + 1) * 4);
    int*   cursor  = (int*)  alloc((size_t)NBINS * 4);
    int*   pbt     = (int*)  alloc((size_t)NBINS * 4);
    int*   pbb     = (int*)  alloc((size_t)(NBINS + 1) * 4);
    int*   offsIB  = (int*)  alloc((size_t)NBINS * 256 * 4);
    int*   offs    = (int*)  alloc((size_t)(N_NODES + 1) * 4);
    int*   bkt     = (int*)  alloc((size_t)BKT_CAP * 4);
    char*  uni     = (char*) alloc((size_t)N_EDGES * 8);   // stg is the larger member
    int2*  stg     = (int2*)uni;
    __half* h1h    = (__half*)uni;
    __half* rh     = h1h + (size_t)N_NODES * F_HID;

    // --- CSR build (dst-major, node segments padded to multiples of 8) ---
    hipMemsetAsync(bincnt, 0, (size_t)NBINS * 4, stream);
    binhist_kernel<<<1024, 256, 0, stream>>>(ei, bincnt);
    binscan_kernel<<<1, 512, 0, stream>>>(bincnt, binbase, cursor);
    partA_kernel<<<NBLK, 256, 0, stream>>>(ei, ew, cursor, stg);
    partB1_kernel<<<NBINS, 256, 0, stream>>>(binbase, stg, offsIB, pbt);
    padscan_kernel<<<1, 512, 0, stream>>>(pbt, pbb, offs);
    partB2_kernel<<<NBINS, 256, 0, stream>>>(binbase, stg, pbb, offsIB, offs, bkt);

    // --- Layer 1: h1 = x@W1 (fp16 table), r = relu(agg(h1)+b1) (fp16 table) ---
    gemm1_kernel<<<N_NODES / 32, 256, 0, stream>>>(x, W1, h1h);
    gather1_kernel<<<N_NODES / 4, 256, 0, stream>>>(offs, bkt, h1h, b1, rh);

    // --- Layer 2 (aggregate-then-transform) + bias2 + log-softmax, fused ---
    gather2_lsm_kernel<<<N_NODES / 4, 256, 0, stream>>>(offs, bkt, rh, W2, b2, out);
}

// Round 11
// 218.810 us; speedup vs baseline: 2.3618x; 1.1710x over previous
//
#include <hip/hip_runtime.h>
#include <hip/hip_fp16.h>
#include <math.h>

#define N_NODES 100000
#define N_EDGES 3200000
#define F_IN    128
#define F_HID   32
#define F_OUT   40
#define NBINS   ((N_NODES + 255) >> 8)   // 391 coarse bins of 256 nodes
#define EPB     4096                     // edges per block in partition pass A
#define NBLK    ((N_EDGES + EPB - 1) / EPB)
#define BKT_CAP (N_EDGES + 8 * N_NODES)  // room for per-node pad-to-8

typedef _Float16 h2_t __attribute__((ext_vector_type(2)));
__device__ __forceinline__ float fdot2u(unsigned a, unsigned b, float c) {
    return __builtin_amdgcn_fdot2(__builtin_bit_cast(h2_t, a),
                                  __builtin_bit_cast(h2_t, b), c, false);
}

// ---------------------------------------------------------------------------
// GEMM1: h1h[N,32] = fp16(x[N,128] @ W1[128,32])
// ---------------------------------------------------------------------------
__global__ __launch_bounds__(256) void gemm1_kernel(const float* __restrict__ x,
                                                    const float* __restrict__ W,
                                                    __half* __restrict__ h1h) {
    __shared__ float Ws[F_IN * F_HID];     // 16 KB
    __shared__ float Xs[32][F_IN + 4];
    const int tid  = threadIdx.x;
    const int row0 = blockIdx.x * 32;

    for (int i = tid; i < (F_IN * F_HID) / 4; i += 256)
        ((float4*)Ws)[i] = ((const float4*)W)[i];

    for (int i = tid; i < 1024; i += 256) {
        int r = i >> 5;
        int c = i & 31;
        ((float4*)&Xs[r][0])[c] = ((const float4*)x)[(size_t)(row0 + r) * (F_IN / 4) + c];
    }
    __syncthreads();

    const int r  = tid >> 3;
    const int c0 = (tid & 7) * 4;
    float a0 = 0.f, a1 = 0.f, a2 = 0.f, a3 = 0.f;
    for (int k = 0; k < F_IN; ++k) {
        const float xv = Xs[r][k];
        const float* wrow = &Ws[k * F_HID + c0];
        a0 += xv * wrow[0];
        a1 += xv * wrow[1];
        a2 += xv * wrow[2];
        a3 += xv * wrow[3];
    }
    const int row = row0 + r;   // grid exact: 3125*32 == N_NODES
    __half2* o = (__half2*)(h1h + (size_t)row * F_HID + c0);
    o[0] = __floats2half2_rn(a0, a1);
    o[1] = __floats2half2_rn(a2, a3);
}

// ---------------------------------------------------------------------------
// Stage 1: per-block bin histogram (LDS, 4-deep preload) -> gcnt[blk][bin].
// ---------------------------------------------------------------------------
__global__ __launch_bounds__(256) void histA_kernel(const int* __restrict__ ei,
                                                    int* __restrict__ gcnt) {
    __shared__ int lh[NBINS];
    const int tid = threadIdx.x;
    const int e0  = blockIdx.x * EPB;
    for (int i = tid; i < NBINS; i += 256) lh[i] = 0;
    __syncthreads();

    for (int base = 0; base < EPB; base += 1024) {
        int d0 = -1, d1 = -1, d2 = -1, d3 = -1;
        const int e = e0 + base + tid;
        if (e < N_EDGES)       d0 = ei[N_EDGES + e] >> 8;
        if (e + 256 < N_EDGES) d1 = ei[N_EDGES + e + 256] >> 8;
        if (e + 512 < N_EDGES) d2 = ei[N_EDGES + e + 512] >> 8;
        if (e + 768 < N_EDGES) d3 = ei[N_EDGES + e + 768] >> 8;
        if (d0 >= 0) atomicAdd(&lh[d0], 1);
        if (d1 >= 0) atomicAdd(&lh[d1], 1);
        if (d2 >= 0) atomicAdd(&lh[d2], 1);
        if (d3 >= 0) atomicAdd(&lh[d3], 1);
    }
    __syncthreads();
    for (int b = tid; b < NBINS; b += 256)
        gcnt[(size_t)blockIdx.x * NBINS + b] = lh[b];
}

// ---------------------------------------------------------------------------
// Stage 2: per-bin column scan over blocks -> pbase[blk][bin] (exclusive,
// relative to bin start) and bintot[bin]. One block per bin.
// ---------------------------------------------------------------------------
__global__ __launch_bounds__(256) void colscan_kernel(const int* __restrict__ gcnt,
                                                      int* __restrict__ pbase,
                                                      int* __restrict__ bintot) {
    __shared__ int s[256];
    __shared__ int carry;
    const int b   = blockIdx.x;
    const int tid = threadIdx.x;
    if (tid == 0) carry = 0;
    __syncthreads();
    for (int c = 0; c < NBLK; c += 256) {
        const int blk = c + tid;
        const int v = (blk < NBLK) ? gcnt[(size_t)blk * NBINS + b] : 0;
        s[tid] = v;
        __syncthreads();
        for (int off = 1; off < 256; off <<= 1) {
            int u = (tid >= off) ? s[tid - off] : 0;
            __syncthreads();
            s[tid] += u;
            __syncthreads();
        }
        if (blk < NBLK) pbase[(size_t)blk * NBINS + b] = carry + s[tid] - v;
        __syncthreads();
        if (tid == 255) carry += s[255];
        __syncthreads();
    }
    if (tid == 0) bintot[b] = carry;
}

// ---------------------------------------------------------------------------
// Stage 3: exclusive scan over 391 bin totals -> binbase[0..NBINS].
// ---------------------------------------------------------------------------
__global__ __launch_bounds__(512) void binscan_kernel(const int* __restrict__ bintot,
                                                      int* __restrict__ binbase) {
    __shared__ int s[512];
    const int t = threadIdx.x;
    const int v = (t < NBINS) ? bintot[t] : 0;
    s[t] = v;
    __syncthreads();
    for (int off = 1; off < 512; off <<= 1) {
        int u = (t >= off) ? s[t - off] : 0;
        __syncthreads();
        s[t] += u;
        __syncthreads();
    }
    if (t <= NBINS) binbase[t] = s[t] - v;
}

// ---------------------------------------------------------------------------
// Stage 4: place. Bases = binbase + pbase (deterministic, no global atomics).
// Rank via in-LDS hist scan; LDS-staged bin-sorted write-out of the FINAL
// packed word (src(17b) | fp16w(15b) << 17) + parallel dlow byte array.
// ---------------------------------------------------------------------------
__global__ __launch_bounds__(256) void placeA_kernel(const int* __restrict__ ei,
                                                     const float* __restrict__ ew,
                                                     const int* __restrict__ gcnt,
                                                     const int* __restrict__ binbase,
                                                     const int* __restrict__ pbase,
                                                     int* __restrict__ stg4,
                                                     unsigned char* __restrict__ dlowg) {
    __shared__ int lhist[512];
    __shared__ int lscan[512];
    __shared__ int lcur[512];
    __shared__ int lwbase[512];
    __shared__ int stmp[256];
    __shared__ int lstg4[EPB];                 // 16 KB
    __shared__ unsigned short lbin[EPB];       // 8 KB
    __shared__ unsigned char ldlow[EPB];       // 4 KB
    const int tid = threadIdx.x;
    const int blk = blockIdx.x;
    const int e0  = blk * EPB;
    const int tot = min(EPB, N_EDGES - e0);

    // load this block's hist + global base
    lhist[tid] = 0; lhist[tid + 256] = 0;
    lwbase[tid] = 0; lwbase[tid + 256] = 0;
    __syncthreads();
    for (int b = tid; b < NBINS; b += 256) {
        lhist[b]  = gcnt[(size_t)blk * NBINS + b];
        lwbase[b] = binbase[b] + pbase[(size_t)blk * NBINS + b];
    }
    __syncthreads();

    // exclusive scan of 512 (each thread owns slots 2t, 2t+1)
    const int ca = lhist[2 * tid];
    const int cb = lhist[2 * tid + 1];
    const int pair = ca + cb;
    stmp[tid] = pair;
    __syncthreads();
    for (int off = 1; off < 256; off <<= 1) {
        int u = (tid >= off) ? stmp[tid - off] : 0;
        __syncthreads();
        stmp[tid] += u;
        __syncthreads();
    }
    const int pexcl = stmp[tid] - pair;
    lscan[2 * tid]     = pexcl;
    lscan[2 * tid + 1] = pexcl + ca;
    lcur[2 * tid]      = pexcl;
    lcur[2 * tid + 1]  = pexcl + ca;
    __syncthreads();

    // rank pass: place bin-sorted into LDS (final packed word), 4-deep preload
    for (int base = 0; base < EPB; base += 1024) {
        int s0 = 0, s1 = 0, s2 = 0, s3 = 0;
        int d0 = -1, d1 = -1, d2 = -1, d3 = -1;
        float w0 = 0.f, w1 = 0.f, w2 = 0.f, w3 = 0.f;
        const int e = e0 + base + tid;
        if (e < N_EDGES)       { s0 = ei[e];       d0 = ei[N_EDGES + e];       w0 = ew[e]; }
        if (e + 256 < N_EDGES) { s1 = ei[e + 256]; d1 = ei[N_EDGES + e + 256]; w1 = ew[e + 256]; }
        if (e + 512 < N_EDGES) { s2 = ei[e + 512]; d2 = ei[N_EDGES + e + 512]; w2 = ew[e + 512]; }
        if (e + 768 < N_EDGES) { s3 = ei[e + 768]; d3 = ei[N_EDGES + e + 768]; w3 = ew[e + 768]; }
        if (d0 >= 0) {
            const int b = d0 >> 8;
            const int p = atomicAdd(&lcur[b], 1);
            lstg4[p] = s0 | ((int)__half_as_ushort(__float2half(w0)) << 17);
            lbin[p] = (unsigned short)b;
            ldlow[p] = (unsigned char)(d0 & 255);
        }
        if (d1 >= 0) {
            const int b = d1 >> 8;
            const int p = atomicAdd(&lcur[b], 1);
            lstg4[p] = s1 | ((int)__half_as_ushort(__float2half(w1)) << 17);
            lbin[p] = (unsigned short)b;
            ldlow[p] = (unsigned char)(d1 & 255);
        }
        if (d2 >= 0) {
            const int b = d2 >> 8;
            const int p = atomicAdd(&lcur[b], 1);
            lstg4[p] = s2 | ((int)__half_as_ushort(__float2half(w2)) << 17);
            lbin[p] = (unsigned short)b;
            ldlow[p] = (unsigned char)(d2 & 255);
        }
        if (d3 >= 0) {
            const int b = d3 >> 8;
            const int p = atomicAdd(&lcur[b], 1);
            lstg4[p] = s3 | ((int)__half_as_ushort(__float2half(w3)) << 17);
            lbin[p] = (unsigned short)b;
            ldlow[p] = (unsigned char)(d3 & 255);
        }
    }
    __syncthreads();

    // write-out: bin-sorted -> bursty near-sequential global stores
    for (int i = tid; i < tot; i += 256) {
        const int b = lbin[i];
        const int pos = lwbase[b] + (i - lscan[b]);
        stg4[pos] = lstg4[i];
        dlowg[pos] = ldlow[i];
    }
}

// ---------------------------------------------------------------------------
// Pass B1: one block per bin. Count per-node degrees from the bin's dlow
// byte slice, pad to 8, in-LDS scan -> in-bin offsets offsIB + padded total.
// ---------------------------------------------------------------------------
__global__ __launch_bounds__(256) void partB1_kernel(const int* __restrict__ binbase,
                                                     const unsigned char* __restrict__ dlowg,
                                                     int* __restrict__ offsIB,
                                                     int* __restrict__ pbt) {
    __shared__ int lcnt[256];
    __shared__ int lsc[256];
    const int tid   = threadIdx.x;
    const int b     = blockIdx.x;
    const int start = binbase[b];
    const int end   = binbase[b + 1];

    lcnt[tid] = 0;
    __syncthreads();
    for (int j = start + tid; j < end; j += 256)
        atomicAdd(&lcnt[dlowg[j]], 1);
    __syncthreads();

    const int padded = (lcnt[tid] + 7) & ~7;
    lsc[tid] = padded;
    __syncthreads();
    for (int off = 1; off < 256; off <<= 1) {
        int u = (tid >= off) ? lsc[tid - off] : 0;
        __syncthreads();
        lsc[tid] += u;
        __syncthreads();
    }
    offsIB[(b << 8) + tid] = lsc[tid] - padded;    // in-bin exclusive
    if (tid == 255) pbt[b] = lsc[255];             // padded bin total
}

// ---------------------------------------------------------------------------
// Scan over 391 padded bin totals -> pbb[0..NBINS]; offs[N] = padded total.
// ---------------------------------------------------------------------------
__global__ __launch_bounds__(512) void padscan_kernel(const int* __restrict__ pbt,
                                                      int* __restrict__ pbb,
                                                      int* __restrict__ offs) {
    __shared__ int s[512];
    const int t = threadIdx.x;
    const int v = (t < NBINS) ? pbt[t] : 0;
    s[t] = v;
    __syncthreads();
    for (int off = 1; off < 512; off <<= 1) {
        int u = (t >= off) ? s[t - off] : 0;
        __syncthreads();
        s[t] += u;
        __syncthreads();
    }
    const int excl = s[t] - v;
    if (t <= NBINS) pbb[t] = excl;
    if (t == NBINS) offs[N_NODES] = excl;
}

// ---------------------------------------------------------------------------
// Pass B2: one block per bin. Final base = pbb[b] + offsIB; write offs[node],
// move the final packed words into bkt, zero-fill the pad slots.
// ---------------------------------------------------------------------------
__global__ __launch_bounds__(256) void partB2_kernel(const int* __restrict__ binbase,
                                                     const int* __restrict__ stg4,
                                                     const unsigned char* __restrict__ dlowg,
                                                     const int* __restrict__ pbb,
                                                     const int* __restrict__ offsIB,
                                                     int* __restrict__ offs,
                                                     int* __restrict__ bkt) {
    __shared__ int lcur[256];
    const int tid  = threadIdx.x;
    const int b    = blockIdx.x;
    const int node = (b << 8) + tid;
    const int base = pbb[b] + offsIB[node];
    const int pend = (tid < 255) ? (pbb[b] + offsIB[node + 1]) : pbb[b + 1];
    lcur[tid] = base;
    if (node < N_NODES) offs[node] = base;
    __syncthreads();

    const int start = binbase[b];
    const int end   = binbase[b + 1];
    for (int j = start + tid; j < end; j += 256) {
        const int word = stg4[j];
        const int pos = atomicAdd(&lcur[dlowg[j]], 1);
        bkt[pos] = word;
    }
    __syncthreads();

    for (int k = lcur[tid]; k < pend; ++k) bkt[k] = 0;
}

// ---------------------------------------------------------------------------
// Shared gather core. Segment [j, jend) is a multiple of 8 entries, j mult 8.
// 8 groups x 8 lanes; lane holds an 8B (4-feature) row fragment.
// Main loop: 8 edges/group (64/wave) via dwordx4 + v_perm + v_dot2_f32_f16.
// ---------------------------------------------------------------------------
__device__ __forceinline__ void gather_acc(const int* __restrict__ bkt,
                                           int j, const int jend,
                                           const char* __restrict__ tbl,
                                           const unsigned sub8, const int g,
                                           float& a0, float& a1, float& a2, float& a3) {
#define PAIR_BODY(PX, PY, RA, RB)                                               \
    {                                                                           \
        const unsigned wp = __builtin_amdgcn_perm((unsigned)(PY) >> 17,         \
                                                  (unsigned)(PX) >> 17,         \
                                                  0x05040100u);                 \
        a0 = fdot2u(__builtin_amdgcn_perm((RB).x, (RA).x, 0x05040100u), wp, a0);\
        a1 = fdot2u(__builtin_amdgcn_perm((RB).x, (RA).x, 0x07060302u), wp, a1);\
        a2 = fdot2u(__builtin_amdgcn_perm((RB).y, (RA).y, 0x05040100u), wp, a2);\
        a3 = fdot2u(__builtin_amdgcn_perm((RB).y, (RA).y, 0x07060302u), wp, a3);\
    }
#define TBL(P) (*(const uint2*)(tbl + (((unsigned)(P) & 0x1FFFFu) << 6) + sub8))
    for (; j + 64 <= jend; j += 64) {
        const int4 pq0 = *(const int4*)&bkt[j + 4 * g];
        const int4 pq1 = *(const int4*)&bkt[j + 32 + 4 * g];
        const uint2 r0 = TBL(pq0.x);
        const uint2 r1 = TBL(pq0.y);
        const uint2 r2 = TBL(pq0.z);
        const uint2 r3 = TBL(pq0.w);
        const uint2 r4 = TBL(pq1.x);
        const uint2 r5 = TBL(pq1.y);
        const uint2 r6 = TBL(pq1.z);
        const uint2 r7 = TBL(pq1.w);
        PAIR_BODY(pq0.x, pq0.y, r0, r1);
        PAIR_BODY(pq0.z, pq0.w, r2, r3);
        PAIR_BODY(pq1.x, pq1.y, r4, r5);
        PAIR_BODY(pq1.z, pq1.w, r6, r7);
    }
    if (j + 32 <= jend) {
        const int4 pq = *(const int4*)&bkt[j + 4 * g];
        const uint2 r0 = TBL(pq.x);
        const uint2 r1 = TBL(pq.y);
        const uint2 r2 = TBL(pq.z);
        const uint2 r3 = TBL(pq.w);
        PAIR_BODY(pq.x, pq.y, r0, r1);
        PAIR_BODY(pq.z, pq.w, r2, r3);
        j += 32;
    }
    if (j + 16 <= jend) {
        const int2 pp = *(const int2*)&bkt[j + 2 * g];
        const uint2 r0 = TBL(pp.x);
        const uint2 r1 = TBL(pp.y);
        PAIR_BODY(pp.x, pp.y, r0, r1);
        j += 16;
    }
    if (j < jend) {   // exactly 8 remain
        const unsigned p = (unsigned)bkt[j + g];
        const unsigned w = p >> 17;            // high half zero
        const uint2 rv = TBL(p);
        a0 = fdot2u(rv.x & 0xFFFFu, w, a0);
        a1 = fdot2u(rv.x >> 16,     w, a1);
        a2 = fdot2u(rv.y & 0xFFFFu, w, a2);
        a3 = fdot2u(rv.y >> 16,     w, a3);
    }
#undef TBL
#undef PAIR_BODY
}

// ---------------------------------------------------------------------------
// Gather 1 + bias1 + ReLU: rh[n] = fp16(relu(sum_e w_e * h1h[src_e] + b1))
// ---------------------------------------------------------------------------
__global__ __launch_bounds__(256) void gather1_kernel(const int* __restrict__ offs,
                                                      const int* __restrict__ bkt,
                                                      const __half* __restrict__ h1h,
                                                      const float* __restrict__ b1,
                                                      __half* __restrict__ rh) {
    const int wave = threadIdx.x >> 6, lane = threadIdx.x & 63;
    const int node = blockIdx.x * 4 + wave;          // grid exact: 25000*4
    const int g    = lane >> 3;
    const int sub  = lane & 7;
    const unsigned sub8 = sub * 8;

    float a0 = 0.f, a1 = 0.f, a2 = 0.f, a3 = 0.f;
    gather_acc(bkt, offs[node], offs[node + 1], (const char*)h1h, sub8, g,
               a0, a1, a2, a3);
    #pragma unroll
    for (int off = 8; off < 64; off <<= 1) {
        a0 += __shfl_xor(a0, off);
        a1 += __shfl_xor(a1, off);
        a2 += __shfl_xor(a2, off);
        a3 += __shfl_xor(a3, off);
    }
    if (g == 0) {
        const float4 bb = ((const float4*)b1)[sub];
        a0 = fmaxf(a0 + bb.x, 0.f);
        a1 = fmaxf(a1 + bb.y, 0.f);
        a2 = fmaxf(a2 + bb.z, 0.f);
        a3 = fmaxf(a3 + bb.w, 0.f);
        uint2 o;
        *(__half2*)&o.x = __floats2half2_rn(a0, a1);
        *(__half2*)&o.y = __floats2half2_rn(a2, a3);
        *(uint2*)((char*)rh + (size_t)node * 64 + sub8) = o;
    }
}

// ---------------------------------------------------------------------------
// Gather 2 + GEMM2 + bias2 + log-softmax, all fused. One wave per node.
// ---------------------------------------------------------------------------
__global__ __launch_bounds__(256) void gather2_lsm_kernel(const int* __restrict__ offs,
                                                          const int* __restrict__ bkt,
                                                          const __half* __restrict__ rh,
                                                          const float* __restrict__ W2,
                                                          const float* __restrict__ b2,
                                                          float* __restrict__ out) {
    __shared__ float W2s[F_HID * F_OUT];   // 5 KB
    __shared__ float rb[4][F_HID];
    const int tid = threadIdx.x;
    for (int i = tid; i < F_HID * F_OUT; i += 256) W2s[i] = W2[i];

    const int wave = tid >> 6, lane = tid & 63;
    const int node = blockIdx.x * 4 + wave;          // grid exact
    const int g    = lane >> 3;
    const int sub  = lane & 7;
    const unsigned sub8 = sub * 8;

    float a0 = 0.f, a1 = 0.f, a2 = 0.f, a3 = 0.f;
    gather_acc(bkt, offs[node], offs[node + 1], (const char*)rh, sub8, g,
               a0, a1, a2, a3);
    #pragma unroll
    for (int off = 8; off < 64; off <<= 1) {
        a0 += __shfl_xor(a0, off);
        a1 += __shfl_xor(a1, off);
        a2 += __shfl_xor(a2, off);
        a3 += __shfl_xor(a3, off);
    }
    if (g == 0)
        ((float4*)&rb[wave][0])[sub] = make_float4(a0, a1, a2, a3);
    __syncthreads();

    float val = -INFINITY;
    if (lane < F_OUT) {
        float acc = b2[lane];
        #pragma unroll
        for (int k = 0; k < F_HID; ++k)
            acc += rb[wave][k] * W2s[k * F_OUT + lane];
        val = acc;
    }
    float m = val;
    for (int off = 32; off; off >>= 1) m = fmaxf(m, __shfl_xor(m, off));
    float ex = (lane < F_OUT) ? __expf(val - m) : 0.f;
    for (int off = 32; off; off >>= 1) ex += __shfl_xor(ex, off);
    if (lane < F_OUT) out[(size_t)node * F_OUT + lane] = val - m - __logf(ex);
}

// ---------------------------------------------------------------------------
extern "C" void kernel_launch(void* const* d_in, const int* in_sizes, int n_in,
                              void* d_out, int out_size, void* d_ws, size_t ws_size,
                              hipStream_t stream) {
    const float* x  = (const float*)d_in[0];
    const int*   ei = (const int*)d_in[1];    // [2, E] int32: row 0 = src, row 1 = dst
    const float* ew = (const float*)d_in[2];
    const float* W1 = (const float*)d_in[3];
    const float* b1 = (const float*)d_in[4];
    const float* W2 = (const float*)d_in[5];
    const float* b2 = (const float*)d_in[6];
    float* out = (float*)d_out;

    // Workspace layout (16B-aligned):
    //   gcnt    : NBLK*NBINS ints   1.22 MB
    //   pbase   : NBLK*NBINS ints   1.22 MB
    //   bintot  : NBINS ints
    //   binbase : NBINS+1 ints
    //   pbt     : NBINS ints
    //   pbb     : NBINS+1 ints
    //   offsIB  : NBINS*256 ints    0.4 MB
    //   offs    : N+1 ints          0.4 MB
    //   bkt     : BKT_CAP ints     16.0 MB
    //   union   : stg4[E] int + dlowg[E] bytes (16 MB, build only)
    //           / h1h + rh fp16 (12.8 MB, after build)
    char* p = (char*)d_ws;
    size_t off = 0;
    auto alloc = [&](size_t bytes) {
        char* r = p + off;
        off += (bytes + 15) & ~(size_t)15;
        return r;
    };
    int*   gcnt    = (int*)  alloc((size_t)NBLK * NBINS * 4);
    int*   pbase   = (int*)  alloc((size_t)NBLK * NBINS * 4);
    int*   bintot  = (int*)  alloc((size_t)NBINS * 4);
    int*   binbase = (int*)  alloc((size_t)(NBINS + 1) * 4);
    int*   pbt     = (int*)  alloc((size_t)NBINS * 4);
    int*   pbb     = (int*)  alloc((size_t)(NBINS + 1) * 4);
    int*   offsIB  = (int*)  alloc((size_t)NBINS * 256 * 4);
    int*   offs    = (int*)  alloc((size_t)(N_NODES + 1) * 4);
    int*   bkt     = (int*)  alloc((size_t)BKT_CAP * 4);
    char*  uni     = (char*) alloc((size_t)N_EDGES * 5);   // stg4 + dlow bytes
    int*   stg4    = (int*)uni;
    unsigned char* dlowg = (unsigned char*)(uni + (size_t)N_EDGES * 4);
    __half* h1h    = (__half*)uni;
    __half* rh     = h1h + (size_t)N_NODES * F_HID;

    // --- CSR build (deterministic bases, no global atomics) ---
    histA_kernel<<<NBLK, 256, 0, stream>>>(ei, gcnt);
    colscan_kernel<<<NBINS, 256, 0, stream>>>(gcnt, pbase, bintot);
    binscan_kernel<<<1, 512, 0, stream>>>(bintot, binbase);
    placeA_kernel<<<NBLK, 256, 0, stream>>>(ei, ew, gcnt, binbase, pbase, stg4, dlowg);
    partB1_kernel<<<NBINS, 256, 0, stream>>>(binbase, dlowg, offsIB, pbt);
    padscan_kernel<<<1, 512, 0, stream>>>(pbt, pbb, offs);
    partB2_kernel<<<NBINS, 256, 0, stream>>>(binbase, stg4, dlowg, pbb, offsIB, offs, bkt);

    // --- Layer 1: h1 = x@W1 (fp16 table), r = relu(agg(h1)+b1) (fp16 table) ---
    gemm1_kernel<<<N_NODES / 32, 256, 0, stream>>>(x, W1, h1h);
    gather1_kernel<<<N_NODES / 4, 256, 0, stream>>>(offs, bkt, h1h, b1, rh);

    // --- Layer 2 (aggregate-then-transform) + bias2 + log-softmax, fused ---
    gather2_lsm_kernel<<<N_NODES / 4, 256, 0, stream>>>(offs, bkt, rh, W2, b2, out);
}